// Round 16
// baseline (429.581 us; speedup 1.0000x reference)
//
#include <hip/hip_runtime.h>
#include <hip/hip_bf16.h>
#include <math.h>

#define E_EDGES 131072
#define NN1 8192
#define NN2 6560          // 16*410
#define NG 16
#define NP1 512
#define KP1 410
#define KP2 205
#define F1 1536
#define EMB 512
#define MAXDEG 256

typedef __hip_bfloat16 bf16;
typedef __attribute__((ext_vector_type(8))) short short8;
typedef __attribute__((ext_vector_type(4))) float f32x4;
typedef __attribute__((ext_vector_type(4))) unsigned short us4;

__device__ inline float wred64(float v){
  #pragma unroll
  for (int o = 32; o; o >>= 1) v += __shfl_down(v, o);
  return v;
}
__device__ inline float b2f_raw(unsigned short u){
  return __uint_as_float((unsigned)u << 16);
}

__device__ __forceinline__ void gld16(const void* g, void* l){
  __builtin_amdgcn_global_load_lds(
      (const __attribute__((address_space(1))) void*)g,
      (__attribute__((address_space(3))) void*)l, 16, 0, 0);
}

__device__ inline void split_store(float v, bf16* __restrict__ ph, bf16* __restrict__ pl){
  bf16 hi = __float2bfloat16(v);
  *ph = hi;
  *pl = __float2bfloat16(v - __bfloat162float(hi));
}

// shared tail: write mean/inv-sigma + pnorm
__device__ inline void bn_tail(float s, float q, int c, float* __restrict__ stats,
    int M, const float* __restrict__ p, float* __restrict__ pnout){
  float mean = s / (float)M;
  float var = fmaxf(q / (float)M - mean*mean, 0.f);
  stats[c] = mean;
  stats[512+c] = 1.f / sqrtf(var + 1e-5f);
  float v = p[c]; v = v*v;
  v = wred64(v);
  __shared__ float red[8];
  int lane = c & 63, wv = c >> 6;
  if (lane == 0) red[wv] = v;
  __syncthreads();
  if (c == 0){ float sm = 0.f; for (int i = 0; i < 8; i++) sm += red[i]; pnout[0] = sqrtf(sm); }
}

// ======================= per-launch precompute =======================
__global__ __launch_bounds__(64) void k_watt1(const float* __restrict__ W1,
    const float* __restrict__ as_, const float* __restrict__ ad_,
    float* __restrict__ was, float* __restrict__ wad, float* __restrict__ M1){
  int b = blockIdx.x, t = threadIdx.x;
  #pragma unroll
  for (int u = 0; u < 4; u++) M1[b*256 + t*4 + u] = 0.f;
  int kind = b / 9, r = b % 9, h = r / 3, f = r % 3;
  const float* att = kind ? ad_ : as_;
  float s = 0.f;
  for (int c = t; c < 512; c += 64) s += W1[f*1536 + h*512 + c] * att[h*512 + c];
  s = wred64(s);
  if (t == 0) (kind ? wad : was)[h*3 + f] = s;
}

__global__ __launch_bounds__(256) void k_m1_acc(const float* __restrict__ W1,
    const float* __restrict__ Wh1, float* __restrict__ M1){
  int j = blockIdx.x*256 + threadIdx.x;
  int r = blockIdx.y; int h = r / 3, f = r % 3;
  int c0 = blockIdx.z*128;
  float acc = 0.f;
  #pragma unroll 4
  for (int c = c0; c < c0 + 128; c++)
    acc += W1[f*1536 + h*512 + c] * Wh1[(size_t)(h*512 + c)*512 + j];
  atomicAdd(&M1[r*512 + j], acc);
}

__global__ __launch_bounds__(256) void k_cvec_acc(
    const float* __restrict__ bc1, const float* __restrict__ Wh1, float* __restrict__ cvec1,
    const float* __restrict__ bc2, const float* __restrict__ Wh2, float* __restrict__ cvec2){
  const float* bc = blockIdx.z ? bc2 : bc1;
  const float* Wh = blockIdx.z ? Wh2 : Wh1;
  float* cvec     = blockIdx.z ? cvec2 : cvec1;
  int j = blockIdx.x*256 + threadIdx.x;
  int i0 = blockIdx.y*128;
  float acc = 0.f;
  #pragma unroll 4
  for (int i = i0; i < i0 + 128; i++) acc += bc[i] * Wh[(size_t)i*512 + j];
  atomicAdd(&cvec[j], acc);
}

// watt2 (y<6) + cvec_init (y==6): grid (2, 7)
__global__ __launch_bounds__(256) void k_watt2(const float* __restrict__ W2,
    const float* __restrict__ as_, const float* __restrict__ ad_,
    float* __restrict__ was2, float* __restrict__ wad2,
    const float* __restrict__ bh1, float* __restrict__ cvec1,
    const float* __restrict__ bh2, float* __restrict__ cvec2){
  int e = blockIdx.x*256 + threadIdx.x;
  int y = blockIdx.y;
  if (y == 6){
    cvec1[e] = bh1[e];
    cvec2[e] = bh2[e];
    return;
  }
  int kind = y / 3, h = y % 3;
  const float* att = kind ? ad_ : as_;
  const float4* row = (const float4*)(W2 + (size_t)e*1536 + h*512);
  const float4* av  = (const float4*)(att + h*512);
  float acc = 0.f;
  #pragma unroll 4
  for (int c4 = 0; c4 < 128; c4++){
    float4 wv = row[c4], a = av[c4];
    acc += wv.x*a.x + wv.y*a.y + wv.z*a.z + wv.w*a.w;
  }
  (kind ? wad2 : was2)[h*512 + e] = acc;
}

// M2 = W2_z @ Wh2_z fp32 GEMM (32x32 tiles), fused transpose+split epilogue; grid (16, 16, 3)
__global__ __launch_bounds__(256) void k_gemm_s(const float* __restrict__ A0,
    const float* __restrict__ B0, bf16* __restrict__ Th, bf16* __restrict__ Tl){
  int z = blockIdx.z;
  const float* A = A0 + (size_t)z*512;            // row stride 1536
  const float* B = B0 + (size_t)z*512*512;        // row stride 512
  __shared__ float As[16][33];
  __shared__ float Bs[16][33];
  __shared__ float tC[32][33];
  int t = threadIdx.x;
  int bm = blockIdx.y*32, bn = blockIdx.x*32;
  int tx = t & 15, ty = t >> 4;
  int ar = t >> 3, ac = (t & 7)*2;
  int br = t >> 4, bc = (t & 15)*2;
  float acc[2][2] = {};
  for (int k0 = 0; k0 < 512; k0 += 16){
    float2 av = *(const float2*)(A + (size_t)(bm+ar)*1536 + k0 + ac);
    As[ac][ar] = av.x; As[ac+1][ar] = av.y;
    float2 bv = *(const float2*)(B + (size_t)(k0+br)*512 + bn + bc);
    Bs[br][bc] = bv.x; Bs[br][bc+1] = bv.y;
    __syncthreads();
    #pragma unroll
    for (int kk = 0; kk < 16; kk++){
      float a0 = As[kk][ty*2], a1 = As[kk][ty*2+1];
      float b0 = Bs[kk][tx*2], b1 = Bs[kk][tx*2+1];
      acc[0][0] += a0*b0; acc[0][1] += a0*b1;
      acc[1][0] += a1*b0; acc[1][1] += a1*b1;
    }
    __syncthreads();
  }
  #pragma unroll
  for (int i = 0; i < 2; i++)
    #pragma unroll
    for (int j = 0; j < 2; j++)
      tC[tx*2+j][ty*2+i] = acc[i][j];             // [n_local][r_local]
  __syncthreads();
  int nl = t >> 3, c0 = (t & 7)*4;
  size_t base = (size_t)(bn + nl)*1536 + (size_t)z*512 + bm + c0;
  #pragma unroll
  for (int u = 0; u < 4; u++)
    split_store(tC[nl][c0+u], &Th[base+u], &Tl[base+u]);
}

// ======================= CSR build =======================
// init: cnt1=1, map=-1 (NN1), cnt2=1 (NN2), bnacc=0 (2048: layer1 then layer2)
__global__ void k_init1(int* __restrict__ cnt1, int* __restrict__ cnt2,
                        int* __restrict__ map, float* __restrict__ bnacc){
  int i = blockIdx.x*blockDim.x + threadIdx.x;
  if (i < NN1){ cnt1[i] = 1; map[i] = -1; }
  if (i < NN2){ cnt2[i] = 1; }
  if (i < 2048){ bnacc[i] = 0.f; }
}
__global__ void k_count1(const int* __restrict__ tgt0, int* __restrict__ cnt, int E){
  int i = blockIdx.x*blockDim.x + threadIdx.x;
  if (i < E) atomicAdd(&cnt[tgt0[i]], 1);
}
__global__ void k_count2(const int* __restrict__ src0, const int* __restrict__ tgt0,
                         const int* __restrict__ map, int* __restrict__ cnt, int E){
  int i = blockIdx.x*blockDim.x + threadIdx.x;
  if (i >= E) return;
  int s = map[src0[i]], tg = map[tgt0[i]];
  if (s >= 0 && tg >= 0) atomicAdd(&cnt[tg], 1);
}
__global__ __launch_bounds__(1024) void k_scan(const int* __restrict__ counts,
    int* __restrict__ off, int* __restrict__ cur, int n){
  __shared__ int sh[1024];
  int t = threadIdx.x;
  int chunk = (n + 1023) >> 10;
  int b = t * chunk; int e = b + chunk; if (e > n) e = n;
  int s = 0;
  for (int i = b; i < e && i < n; i++) s += counts[i];
  sh[t] = s; __syncthreads();
  for (int o = 1; o < 1024; o <<= 1){
    int v = (t >= o) ? sh[t-o] : 0;
    __syncthreads();
    sh[t] += v;
    __syncthreads();
  }
  int run = (t > 0) ? sh[t-1] : 0;
  for (int i = b; i < e && i < n; i++){ int c = counts[i]; off[i] = run; cur[i] = run; run += c; }
  if (t == 1023) off[n] = sh[1023];
}
__global__ void k_fill1(const int* __restrict__ src0, const int* __restrict__ tgt0,
                        int* __restrict__ cur, int* __restrict__ esrc, int E, int nn){
  int i = blockIdx.x*blockDim.x + threadIdx.x;
  if (i >= E + nn) return;
  int s, tg;
  if (i < E){ s = src0[i]; tg = tgt0[i]; } else { s = i - E; tg = s; }
  int pos = atomicAdd(&cur[tg], 1);
  esrc[pos] = s;
}
__global__ void k_fill2(const int* __restrict__ src0, const int* __restrict__ tgt0,
                        const int* __restrict__ map, int* __restrict__ cur,
                        int* __restrict__ esrc, int E, int nn){
  int i = blockIdx.x*blockDim.x + threadIdx.x;
  if (i >= E + nn) return;
  int s, tg;
  if (i < E){
    s = map[src0[i]]; tg = map[tgt0[i]];
    if (s < 0 || tg < 0) return;
  } else { s = i - E; tg = s; }
  int pos = atomicAdd(&cur[tg], 1);
  esrc[pos] = s;
}

// ======================= layer 1: aggregate raw x (3 features) =======================
__global__ __launch_bounds__(64) void k_agg1(
    const float* __restrict__ x, const int* __restrict__ off, const int* __restrict__ esrc,
    const float* __restrict__ was, const float* __restrict__ wad,
    float* __restrict__ aggx){          // [n*9], idx h*3+f
  int n = blockIdx.x, t = threadIdx.x;  // 64 threads = 1 wave
  __shared__ float xs[MAXDEG][3];
  __shared__ float al[MAXDEG*3];
  __shared__ float mh[3], dh[3];
  int s0 = off[n]; int deg = off[n+1] - s0; if (deg > MAXDEG) deg = MAXDEG;
  float ad0, ad1, ad2;
  {
    float x0 = x[n*3], x1 = x[n*3+1], x2 = x[n*3+2];
    ad0 = x0*wad[0] + x1*wad[1] + x2*wad[2];
    ad1 = x0*wad[3] + x1*wad[4] + x2*wad[5];
    ad2 = x0*wad[6] + x1*wad[7] + x2*wad[8];
  }
  for (int e = t; e < deg; e += 64){
    int s = esrc[s0 + e];
    float x0 = x[s*3], x1 = x[s*3+1], x2 = x[s*3+2];
    xs[e][0] = x0; xs[e][1] = x1; xs[e][2] = x2;
    float v0 = x0*was[0] + x1*was[1] + x2*was[2] + ad0;
    float v1 = x0*was[3] + x1*was[4] + x2*was[5] + ad1;
    float v2 = x0*was[6] + x1*was[7] + x2*was[8] + ad2;
    al[e*3+0] = v0 > 0.f ? v0 : 0.2f*v0;
    al[e*3+1] = v1 > 0.f ? v1 : 0.2f*v1;
    al[e*3+2] = v2 > 0.f ? v2 : 0.2f*v2;
  }
  __syncthreads();
  if (t < 3){
    float m = -INFINITY;
    for (int e = 0; e < deg; e++) m = fmaxf(m, al[e*3+t]);
    float d = 0.f;
    for (int e = 0; e < deg; e++) d += expf(al[e*3+t] - m);
    mh[t] = m; dh[t] = 1.f / fmaxf(d, 1e-16f);
  }
  __syncthreads();
  float acc[9] = {0,0,0,0,0,0,0,0,0};
  for (int e = t; e < deg; e += 64){
    #pragma unroll
    for (int h = 0; h < 3; h++){
      float a = expf(al[e*3+h] - mh[h]) * dh[h];
      acc[h*3+0] += a * xs[e][0];
      acc[h*3+1] += a * xs[e][1];
      acc[h*3+2] += a * xs[e][2];
    }
  }
  #pragma unroll
  for (int q = 0; q < 9; q++){
    float v = wred64(acc[q]);
    if (t == 0) aggx[(size_t)n*9 + q] = v;
  }
}

// h1[n,j] = relu(cvec[j] + sum_q aggx[n,q]*M1[q,j]) -> bf16 ; 8 nodes per block
// fused BN partial stats: per-column sum/sq over the block's 8 rows -> atomicAdd(bnacc)
__global__ __launch_bounds__(256) void k_h1(const float* __restrict__ aggx,
    const float* __restrict__ M1, const float* __restrict__ cvec, bf16* __restrict__ hout,
    float* __restrict__ bnacc){
  __shared__ float sM[9*512];
  __shared__ float sC[512];
  __shared__ float sA[8*9];
  int t = threadIdx.x; int n0 = blockIdx.x*8;
  for (int i = t; i < 9*512; i += 256) sM[i] = M1[i];
  for (int i = t; i < 512; i += 256) sC[i] = cvec[i];
  for (int i = t; i < 72; i += 256) sA[i] = aggx[(size_t)n0*9 + i];
  __syncthreads();
  #pragma unroll
  for (int k2 = 0; k2 < 2; k2++){
    int j = t + k2*256;
    float ls = 0.f, lq = 0.f;
    #pragma unroll
    for (int i = 0; i < 8; i++){
      float a = sC[j];
      #pragma unroll
      for (int q = 0; q < 9; q++) a += sA[i*9+q] * sM[q*512+j];
      a = fmaxf(a, 0.f);
      hout[(size_t)(n0+i)*512 + j] = __float2bfloat16(a);
      ls += a; lq += a*a;
    }
    atomicAdd(&bnacc[j], ls);
    atomicAdd(&bnacc[512 + j], lq);
  }
}

// ======================= BN / score =======================
// totals already in bnacc (no loop)
__global__ void k_bn_final_1(const float* __restrict__ bnacc,
    float* __restrict__ stats, int M, const float* __restrict__ p, float* __restrict__ pnout){
  int c = threadIdx.x;
  bn_tail(bnacc[c], bnacc[512 + c], c, stats, M, p, pnout);
}
// score only (y not materialized), bf16 h
__global__ __launch_bounds__(256) void k_score(
    const bf16* __restrict__ h, const float* __restrict__ stats,
    const float* __restrict__ g_, const float* __restrict__ be,
    const float* __restrict__ p, const float* __restrict__ pn,
    float* __restrict__ score){
  int r = blockIdx.x, t = threadIdx.x;
  float dot = 0.f;
  #pragma unroll
  for (int k = 0; k < 2; k++){
    int c = t + k*256;
    float v = (__bfloat162float(h[(size_t)r*EMB + c]) - stats[c]) * stats[512+c] * g_[c] + be[c];
    dot += v * p[c];
  }
  dot = wred64(dot);
  __shared__ float red[4];
  int lane = t & 63, wv = t >> 6;
  if (lane == 0) red[wv] = dot;
  __syncthreads();
  if (t == 0) score[r] = tanhf((red[0]+red[1]+red[2]+red[3]) / pn[0]);
}

// ======================= top-k =======================
__global__ __launch_bounds__(512) void k_topk_sort(
    const float* __restrict__ score, int* __restrict__ map,
    int* __restrict__ topi, float* __restrict__ tops, int n_per, int K){
  int g = blockIdx.x, t = threadIdx.x;     // 512 threads, 1 elem each
  __shared__ float sk[512];
  __shared__ int si[512];
  if (t < n_per){ sk[t] = score[g*n_per + t]; si[t] = t; }
  else { sk[t] = -INFINITY; si[t] = 0x7fffffff; }
  __syncthreads();
  for (int k = 2; k <= 512; k <<= 1){
    for (int j = k >> 1; j > 0; j >>= 1){
      int l = t ^ j;
      if (l > t){
        float ki = sk[t], kl = sk[l]; int ii = si[t], il = si[l];
        bool before_l = (kl > ki) || (kl == ki && il < ii);
        bool up = ((t & k) == 0);
        if (up == before_l){ sk[t]=kl; sk[l]=ki; si[t]=il; si[l]=ii; }
      }
      __syncthreads();
    }
  }
  if (t < K){
    if (map) map[g*n_per + si[t]] = g*K + t;
    topi[g*K + t] = si[t];
    tops[g*K + t] = sk[t];
  }
}

// gather + on-the-fly BN + scale -> bf16; optionally fused layer-2 attention dots
__global__ __launch_bounds__(256) void k_topk_gather(
    const bf16* __restrict__ h, const float* __restrict__ stats,
    const float* __restrict__ gm, const float* __restrict__ be,
    const int* __restrict__ topi, const float* __restrict__ tops,
    bf16* __restrict__ xn, int n_per, int K,
    const float* __restrict__ was2, const float* __restrict__ wad2,
    float* __restrict__ aso, float* __restrict__ ado){
  int row = blockIdx.x, t = threadIdx.x;
  int gr = row / K, i = row - gr*K;
  int sidx = topi[gr*K + i];
  float s = tops[gr*K + i];
  const bf16* src = h + ((size_t)(gr*n_per + sidx))*EMB;
  bf16* dst = xn + (size_t)row*EMB;
  int c0 = t, c1 = t + 256;
  float v0 = ((__bfloat162float(src[c0]) - stats[c0]) * stats[512+c0] * gm[c0] + be[c0]) * s;
  float v1 = ((__bfloat162float(src[c1]) - stats[c1]) * stats[512+c1] * gm[c1] + be[c1]) * s;
  dst[c0] = __float2bfloat16(v0);
  dst[c1] = __float2bfloat16(v1);
  if (was2){
    float a[6];
    #pragma unroll
    for (int hh = 0; hh < 3; hh++){
      a[hh]   = v0*was2[hh*512 + c0] + v1*was2[hh*512 + c1];
      a[3+hh] = v0*wad2[hh*512 + c0] + v1*wad2[hh*512 + c1];
    }
    __shared__ float red[6][4];
    int lane = t & 63, wv = t >> 6;
    #pragma unroll
    for (int q = 0; q < 6; q++){ float v = wred64(a[q]); if (lane==0) red[q][wv]=v; }
    __syncthreads();
    if (t < 6){
      float sm = red[t][0]+red[t][1]+red[t][2]+red[t][3];
      if (t < 3) aso[row*3+t] = sm; else ado[row*3+(t-3)] = sm;
    }
  }
}

// ======================= pooling (bf16 input) =======================
__global__ __launch_bounds__(256) void k_pool_partial(const bf16* __restrict__ xn,
    float* __restrict__ pmax, float* __restrict__ psum, int K){
  int g = blockIdx.x, ch = blockIdx.y, t = threadIdx.x;
  int rs = (K + 15) >> 4;
  int r0 = ch*rs, r1 = r0 + rs; if (r1 > K) r1 = K;
  #pragma unroll
  for (int k = 0; k < 2; k++){
    int c = t + k*256;
    float mx = -INFINITY, sm = 0.f;
    for (int r = r0; r < r1; r++){
      float v = __bfloat162float(xn[((size_t)(g*K + r))*EMB + c]);
      mx = fmaxf(mx, v); sm += v;
    }
    pmax[((size_t)(g*16 + ch))*EMB + c] = mx;
    psum[((size_t)(g*16 + ch))*EMB + c] = sm;
  }
}
__global__ __launch_bounds__(512) void k_pool_final(const float* __restrict__ pmax,
    const float* __restrict__ psum, float* __restrict__ cat, int K){
  int g = blockIdx.x, c = threadIdx.x;
  float mx = -INFINITY, sm = 0.f;
  #pragma unroll
  for (int ch = 0; ch < 16; ch++){
    size_t o = ((size_t)(g*16 + ch))*EMB + c;
    mx = fmaxf(mx, pmax[o]); sm += psum[o];
  }
  cat[g*1024 + c] = mx;
  cat[g*1024 + 512 + c] = sm / (float)K;
}

// ======================= layer 2 aggregation (bf16 xn input) =======================
__global__ __launch_bounds__(256) void k_agg2(
    const bf16* __restrict__ xn, const float* __restrict__ aso, const float* __restrict__ ado,
    const int* __restrict__ off, const int* __restrict__ esrc,
    bf16* __restrict__ oh){
  int n = blockIdx.x, t = threadIdx.x;
  __shared__ int srcs[MAXDEG];
  __shared__ float al[MAXDEG*3];
  __shared__ float mh[3], dh[3];
  int s0 = off[n]; int deg = off[n+1] - s0; if (deg > MAXDEG) deg = MAXDEG;
  for (int e = t; e < deg; e += 256) srcs[e] = esrc[s0 + e];
  __syncthreads();
  float ad0 = ado[n*3+0], ad1 = ado[n*3+1], ad2 = ado[n*3+2];
  for (int e = t; e < deg; e += 256){
    int s = srcs[e];
    float v0 = aso[s*3+0] + ad0, v1 = aso[s*3+1] + ad1, v2 = aso[s*3+2] + ad2;
    al[e*3+0] = v0 > 0.f ? v0 : 0.2f*v0;
    al[e*3+1] = v1 > 0.f ? v1 : 0.2f*v1;
    al[e*3+2] = v2 > 0.f ? v2 : 0.2f*v2;
  }
  __syncthreads();
  if (t < 3){
    float m = -INFINITY;
    for (int e = 0; e < deg; e++) m = fmaxf(m, al[e*3+t]);
    float d = 0.f;
    for (int e = 0; e < deg; e++) d += expf(al[e*3+t] - m);
    mh[t] = m; dh[t] = 1.f / fmaxf(d, 1e-16f);
  }
  __syncthreads();
  for (int e = t; e < deg; e += 256){
    al[e*3+0] = expf(al[e*3+0]-mh[0])*dh[0];
    al[e*3+1] = expf(al[e*3+1]-mh[1])*dh[1];
    al[e*3+2] = expf(al[e*3+2]-mh[2])*dh[2];
  }
  __syncthreads();
  float acc[2][3] = {};
  for (int e = 0; e < deg; e++){
    int s = srcs[e];
    float a0 = al[e*3], a1 = al[e*3+1], a2 = al[e*3+2];
    #pragma unroll
    for (int k = 0; k < 2; k++){
      float v = __bfloat162float(xn[(size_t)s*512 + t + k*256]);
      acc[k][0] += a0*v; acc[k][1] += a1*v; acc[k][2] += a2*v;
    }
  }
  #pragma unroll
  for (int k = 0; k < 2; k++){
    int c = t + k*256;
    #pragma unroll
    for (int h = 0; h < 3; h++)
      oh[(size_t)n*1536 + h*512 + c] = __float2bfloat16(acc[k][h]);
  }
}

// ======================= bf16-A x split-bf16-B MFMA GEMM =======================
// 128x64 tile, BK=64, XOR-swizzled LDS, double-buffered prefetch-after-barrier.
// bf16 C output + fused BN partial stats (atomicAdd into bnacc[0..511]=sum, [512..1023]=sq).
// flat grid Mtiles*8 (bm-major); wave w: rows (w>>1)*64.. x cols (w&1)*32..
__global__ __launch_bounds__(256, 2) void k_gemm_mfma(
    const bf16* __restrict__ Ah,
    const bf16* __restrict__ Bh, const bf16* __restrict__ Bl,   // [N][K] row-major
    const float* __restrict__ bias, bf16* __restrict__ C,
    float* __restrict__ bnacc,
    int M, int N, int K, int Mtiles){
  __shared__ __align__(16) unsigned short lds[2][16384];   // 64 KB total
  int t = threadIdx.x, w = t >> 6, lane = t & 63;
  int q = lane >> 4, l16 = lane & 15;
  int bmi = (int)blockIdx.x % Mtiles, bni = (int)blockIdx.x / Mtiles;
  int bm = bmi * 128, bn = bni * 64;

  int lr = lane >> 3, lc = lane & 7;
  int kg = ((lc ^ lr) & 7) * 8;          // swizzled global k element offset
  int ro = w*8 + lr;
  int m0 = bm + ro, m1 = bm + 32 + ro, m2 = bm + 64 + ro, m3 = bm + 96 + ro;
  if (m0 >= M) m0 = M-1;  if (m1 >= M) m1 = M-1;
  if (m2 >= M) m2 = M-1;  if (m3 >= M) m3 = M-1;
  int n0 = bn + ro, n1 = bn + 32 + ro;
  const bf16* ptr[8];
  ptr[0] = Ah + (size_t)m0*K + kg;
  ptr[1] = Ah + (size_t)m1*K + kg;
  ptr[2] = Ah + (size_t)m2*K + kg;
  ptr[3] = Ah + (size_t)m3*K + kg;
  ptr[4] = Bh + (size_t)n0*K + kg;
  ptr[5] = Bh + (size_t)n1*K + kg;
  ptr[6] = Bl + (size_t)n0*K + kg;
  ptr[7] = Bl + (size_t)n1*K + kg;
  const int dof[8] = {0, 2048, 4096, 6144, 8192, 10240, 12288, 14336};

  int wm = (w >> 1) * 64, wn = (w & 1) * 32;
  f32x4 acc[4][2];
  #pragma unroll
  for (int i = 0; i < 4; i++)
    #pragma unroll
    for (int j = 0; j < 2; j++)
      acc[i][j] = (f32x4){0.f, 0.f, 0.f, 0.f};

  #pragma unroll
  for (int u = 0; u < 8; u++){
    gld16(ptr[u], &lds[0][dof[u] + w*512]);
    ptr[u] += 64;
  }

  int nit = K >> 6;
  for (int it = 0; it < nit; it++){
    __syncthreads();
    int cur = it & 1;
    if (it + 1 < nit){
      int nxt = cur ^ 1;
      #pragma unroll
      for (int u = 0; u < 8; u++){
        gld16(ptr[u], &lds[nxt][dof[u] + w*512]);
        ptr[u] += 64;
      }
    }
    const unsigned short* L = lds[cur];
    #pragma unroll
    for (int ks = 0; ks < 2; ks++){
      short8 ah[4], bh2[2], bl2[2];
      int gc = ks*4 + q;
      #pragma unroll
      for (int i = 0; i < 4; i++){
        int r = wm + i*16 + l16;
        ah[i] = *(const short8*)(L + r*64 + ((gc ^ (r & 7)) << 3));
      }
      #pragma unroll
      for (int j = 0; j < 2; j++){
        int r = wn + j*16 + l16;
        int so = ((gc ^ (r & 7)) << 3);
        bh2[j] = *(const short8*)(L + 8192  + r*64 + so);
        bl2[j] = *(const short8*)(L + 12288 + r*64 + so);
      }
      #pragma unroll
      for (int i = 0; i < 4; i++)
        #pragma unroll
        for (int j = 0; j < 2; j++){
          acc[i][j] = __builtin_amdgcn_mfma_f32_16x16x32_bf16(ah[i], bh2[j], acc[i][j], 0, 0, 0);
          acc[i][j] = __builtin_amdgcn_mfma_f32_16x16x32_bf16(ah[i], bl2[j], acc[i][j], 0, 0, 0);
        }
    }
  }

  // epilogue: relu + bf16 store + per-column BN partials
  __syncthreads();                       // LDS now free for reduction scratch
  float* cs = (float*)&lds[0][0];        // [2][64] col sums | [2][64] col sqs
  float* cq = cs + 128;
  int slot = w >> 1;
  #pragma unroll
  for (int j = 0; j < 2; j++){
    int c_local = wn + j*16 + l16;
    int c = bn + c_local;
    float bv = bias ? bias[c] : 0.f;
    float ls = 0.f, lq = 0.f;
    #pragma unroll
    for (int i = 0; i < 4; i++){
      int rb = bm + wm + i*16 + q*4;
      #pragma unroll
      for (int e = 0; e < 4; e++){
        int r = rb + e;
        if (r < M){
          float v = fmaxf(acc[i][j][e] + bv, 0.f);
          C[(size_t)r*N + c] = __float2bfloat16(v);
          ls += v; lq += v*v;
        }
      }
    }
    ls += __shfl_xor(ls, 16); ls += __shfl_xor(ls, 32);
    lq += __shfl_xor(lq, 16); lq += __shfl_xor(lq, 32);
    if (q == 0){ cs[slot*64 + c_local] = ls; cq[slot*64 + c_local] = lq; }
  }
  __syncthreads();
  if (t < 64){
    atomicAdd(&bnacc[bn + t],        cs[t] + cs[64 + t]);
    atomicAdd(&bnacc[512 + bn + t],  cq[t] + cq[64 + t]);
  }
}

// ======================= head =======================
__global__ __launch_bounds__(256) void k_head1(const float* __restrict__ c1,
    const float* __restrict__ c2, const float* __restrict__ Wl1,
    const float* __restrict__ bl1, float* __restrict__ t1){
  int g = blockIdx.y;
  int jj = threadIdx.x & 63, kc = threadIdx.x >> 6;
  int j = blockIdx.x*64 + jj;
  float acc = 0.f;
  for (int k = kc*256; k < kc*256 + 256; k++){
    float xg = c1[g*1024 + k] + c2[g*1024 + k];
    acc += xg * Wl1[(size_t)k*512 + j];
  }
  __shared__ float red[4][64];
  red[kc][jj] = acc;
  __syncthreads();
  if (kc == 0){
    float v = red[0][jj]+red[1][jj]+red[2][jj]+red[3][jj] + bl1[j];
    t1[g*512 + j] = fmaxf(v, 0.f);
  }
}
__global__ __launch_bounds__(256) void k_head2(const float* __restrict__ t1,
    const float* __restrict__ Wl2, const float* __restrict__ bl2, float* __restrict__ out){
  int g = blockIdx.y;
  int jj = threadIdx.x & 63, kc = threadIdx.x >> 6;
  int j = blockIdx.x*64 + jj;
  float acc = 0.f;
  for (int k = kc*128; k < kc*128 + 128; k++)
    acc += t1[g*512 + k] * Wl2[(size_t)k*256 + j];
  __shared__ float red[4][64];
  red[kc][jj] = acc;
  __syncthreads();
  if (kc == 0)
    out[g*256 + j] = red[0][jj]+red[1][jj]+red[2][jj]+red[3][jj] + bl2[j];
}

extern "C" void kernel_launch(void* const* d_in, const int* in_sizes, int n_in,
                              void* d_out, int out_size, void* d_ws, size_t ws_size,
                              hipStream_t stream){
  const float* x   = (const float*)d_in[0];
  const int*   ei  = (const int*)d_in[1];
  const float* W1  = (const float*)d_in[2];
  const float* as1 = (const float*)d_in[3];
  const float* ad1 = (const float*)d_in[4];
  const float* bc1 = (const float*)d_in[5];
  const float* Wh1 = (const float*)d_in[6];
  const float* bh1 = (const float*)d_in[7];
  const float* g1  = (const float*)d_in[8];
  const float* be1 = (const float*)d_in[9];
  const float* p1  = (const float*)d_in[10];
  const float* W2  = (const float*)d_in[11];
  const float* as2 = (const float*)d_in[12];
  const float* ad2 = (const float*)d_in[13];
  const float* bc2 = (const float*)d_in[14];
  const float* Wh2 = (const float*)d_in[15];
  const float* bh2 = (const float*)d_in[16];
  const float* g2  = (const float*)d_in[17];
  const float* be2 = (const float*)d_in[18];
  const float* p2  = (const float*)d_in[19];
  const float* Wl1 = (const float*)d_in[20];
  const float* bl1 = (const float*)d_in[21];
  const float* Wl2 = (const float*)d_in[22];
  const float* bl2 = (const float*)d_in[23];
  float* out = (float*)d_out;

  const int* src0 = ei;
  const int* tgt0 = ei + E_EDGES;

  // ---- workspace layout ----
  bf16* Cc     = (bf16*)d_ws;                        // 8192*512 bf16 (h1 -> h2)
  bf16* xn1    = Cc + (size_t)NN1*EMB;               // 6560*512 bf16
  bf16* xn2    = xn1 + (size_t)NN2*EMB;              // 3280*512 bf16
  float* aggx1 = (float*)(xn2 + (size_t)NG*KP2*EMB + 8); // 8192*9
  float* M1    = aggx1 + (size_t)NN1*9;              // 9*512
  float* was2  = M1 + 9*EMB;                         // 3*512
  float* wad2  = was2 + 3*EMB;
  float* cvec1 = wad2 + 3*EMB;                       // 512
  float* cvec2 = cvec1 + EMB;
  float* was1  = cvec2 + EMB;                        // 16
  float* wad1  = was1 + 16;
  float* stats = wad1 + 16;                          // 1024
  float* bnacc = stats + 1024;                       // 2048 (layer1 | layer2)
  float* pn    = bnacc + 2048;                       // 16
  float* score = pn + 16;                            // 8192
  float* cat1  = score + NN1;                        // 16*1024
  float* cat2  = cat1 + NG*1024;
  float* t1h   = cat2 + NG*1024;                     // 16*512
  float* pmax  = t1h + NG*EMB;                       // 16*16*512
  float* psum  = pmax + NG*16*EMB;
  float* aso2  = psum + NG*16*EMB;                   // 6560*3
  float* ado2  = aso2 + NN2*3;
  float* tops  = ado2 + NN2*3;                       // 16*410
  bf16* aggx2h = (bf16*)(tops + NG*KP1);             // 6560*1536 (bf16, hi only)
  bf16* M2Th   = aggx2h + (size_t)NN2*F1;            // 512*1536
  bf16* M2Tl   = M2Th + (size_t)EMB*F1;
  int* map     = (int*)(M2Tl + (size_t)EMB*F1);      // 8192
  int* cnt1    = map + NN1;
  int* off1    = cnt1 + NN1;                         // 8200
  int* cur1    = off1 + NN1 + 8;
  int* esrc1   = cur1 + NN1;                         // 139264
  int* cnt2    = esrc1 + (E_EDGES + NN1);
  int* off2    = cnt2 + NN2;                         // 6568
  int* cur2    = off2 + NN2 + 8;
  int* esrc2   = cur2 + NN2;                         // 137700 (pad)
  int* topi    = esrc2 + 137700;                     // 16*410

  // ---- precompute ----
  k_init1<<<(NN1+255)/256,256,0,stream>>>(cnt1,cnt2,map,bnacc);
  k_watt1<<<18,64,0,stream>>>(W1,as1,ad1,was1,wad1,M1);
  k_m1_acc<<<dim3(2,9,4),256,0,stream>>>(W1,Wh1,M1);
  k_watt2<<<dim3(2,7),256,0,stream>>>(W2,as2,ad2,was2,wad2,bh1,cvec1,bh2,cvec2);
  k_cvec_acc<<<dim3(2,12,2),256,0,stream>>>(bc1,Wh1,cvec1,bc2,Wh2,cvec2);
  k_gemm_s<<<dim3(16,16,3),256,0,stream>>>(W2,Wh2,M2Th,M2Tl);

  // ---- layer 1 ----
  k_count1<<<(E_EDGES+255)/256,256,0,stream>>>(tgt0,cnt1,E_EDGES);
  k_scan<<<1,1024,0,stream>>>(cnt1,off1,cur1,NN1);
  k_fill1<<<(E_EDGES+NN1+255)/256,256,0,stream>>>(src0,tgt0,cur1,esrc1,E_EDGES,NN1);
  k_agg1<<<NN1,64,0,stream>>>(x,off1,esrc1,was1,wad1,aggx1);
  k_h1<<<NN1/8,256,0,stream>>>(aggx1,M1,cvec1,Cc,bnacc);
  k_bn_final_1<<<1,512,0,stream>>>(bnacc,stats,NN1,p1,pn);
  k_score<<<NN1,256,0,stream>>>(Cc,stats,g1,be1,p1,pn,score);
  k_topk_sort<<<NG,512,0,stream>>>(score,map,topi,tops,NP1,KP1);
  k_topk_gather<<<NG*KP1,256,0,stream>>>(Cc,stats,g1,be1,topi,tops,xn1,NP1,KP1,
      was2,wad2,aso2,ado2);
  k_pool_partial<<<dim3(NG,16),256,0,stream>>>(xn1,pmax,psum,KP1);
  k_pool_final<<<NG,512,0,stream>>>(pmax,psum,cat1,KP1);

  // ---- layer 2 ----
  k_count2<<<(E_EDGES+255)/256,256,0,stream>>>(src0,tgt0,map,cnt2,E_EDGES);
  k_scan<<<1,1024,0,stream>>>(cnt2,off2,cur2,NN2);
  k_fill2<<<(E_EDGES+NN2+255)/256,256,0,stream>>>(src0,tgt0,map,cur2,esrc2,E_EDGES,NN2);
  k_agg2<<<NN2,256,0,stream>>>(xn1,aso2,ado2,off2,esrc2,aggx2h);
  k_gemm_mfma<<<52*8,256,0,stream>>>(aggx2h,M2Th,M2Tl,cvec2,Cc,bnacc+1024,NN2,EMB,F1,52);
  k_bn_final_1<<<1,512,0,stream>>>(bnacc+1024,stats,NN2,p2,pn+1);
  k_score<<<NN2,256,0,stream>>>(Cc,stats,g2,be2,p2,pn+1,score);
  k_topk_sort<<<NG,512,0,stream>>>(score,(int*)nullptr,topi,tops,KP1,KP2);
  k_topk_gather<<<NG*KP2,256,0,stream>>>(Cc,stats,g2,be2,topi,tops,xn2,KP1,KP2,
      (const float*)nullptr,(const float*)nullptr,(float*)nullptr,(float*)nullptr);
  k_pool_partial<<<dim3(NG,16),256,0,stream>>>(xn2,pmax,psum,KP2);
  k_pool_final<<<NG,512,0,stream>>>(pmax,psum,cat2,KP2);

  // ---- head ----
  k_head1<<<dim3(8,NG),256,0,stream>>>(cat1,cat2,Wl1,bl1,t1h);
  k_head2<<<dim3(4,NG),256,0,stream>>>(t1h,Wl2,bl2,out);
}

// Round 17
// 415.456 us; speedup vs baseline: 1.0340x; 1.0340x over previous
//
#include <hip/hip_runtime.h>
#include <hip/hip_bf16.h>
#include <math.h>

#define E_EDGES 131072
#define NN1 8192
#define NN2 6560          // 16*410
#define NG 16
#define NP1 512
#define KP1 410
#define KP2 205
#define F1 1536
#define EMB 512
#define MAXDEG 256
#define BNCH 256          // bn_stats chunks (layer 1)

typedef __hip_bfloat16 bf16;
typedef __attribute__((ext_vector_type(8))) short short8;
typedef __attribute__((ext_vector_type(4))) float f32x4;
typedef __attribute__((ext_vector_type(4))) unsigned short us4;

__device__ inline float wred64(float v){
  #pragma unroll
  for (int o = 32; o; o >>= 1) v += __shfl_down(v, o);
  return v;
}
__device__ inline float b2f_raw(unsigned short u){
  return __uint_as_float((unsigned)u << 16);
}

__device__ __forceinline__ void gld16(const void* g, void* l){
  __builtin_amdgcn_global_load_lds(
      (const __attribute__((address_space(1))) void*)g,
      (__attribute__((address_space(3))) void*)l, 16, 0, 0);
}

__device__ inline void split_store(float v, bf16* __restrict__ ph, bf16* __restrict__ pl){
  bf16 hi = __float2bfloat16(v);
  *ph = hi;
  *pl = __float2bfloat16(v - __bfloat162float(hi));
}

// shared tail: write mean/inv-sigma + pnorm
__device__ inline void bn_tail(float s, float q, int c, float* __restrict__ stats,
    int M, const float* __restrict__ p, float* __restrict__ pnout){
  float mean = s / (float)M;
  float var = fmaxf(q / (float)M - mean*mean, 0.f);
  stats[c] = mean;
  stats[512+c] = 1.f / sqrtf(var + 1e-5f);
  float v = p[c]; v = v*v;
  v = wred64(v);
  __shared__ float red[8];
  int lane = c & 63, wv = c >> 6;
  if (lane == 0) red[wv] = v;
  __syncthreads();
  if (c == 0){ float sm = 0.f; for (int i = 0; i < 8; i++) sm += red[i]; pnout[0] = sqrtf(sm); }
}

// ======================= per-launch precompute =======================
__global__ __launch_bounds__(64) void k_watt1(const float* __restrict__ W1,
    const float* __restrict__ as_, const float* __restrict__ ad_,
    float* __restrict__ was, float* __restrict__ wad, float* __restrict__ M1){
  int b = blockIdx.x, t = threadIdx.x;
  #pragma unroll
  for (int u = 0; u < 4; u++) M1[b*256 + t*4 + u] = 0.f;
  int kind = b / 9, r = b % 9, h = r / 3, f = r % 3;
  const float* att = kind ? ad_ : as_;
  float s = 0.f;
  for (int c = t; c < 512; c += 64) s += W1[f*1536 + h*512 + c] * att[h*512 + c];
  s = wred64(s);
  if (t == 0) (kind ? wad : was)[h*3 + f] = s;
}

__global__ __launch_bounds__(256) void k_m1_acc(const float* __restrict__ W1,
    const float* __restrict__ Wh1, float* __restrict__ M1){
  int j = blockIdx.x*256 + threadIdx.x;
  int r = blockIdx.y; int h = r / 3, f = r % 3;
  int c0 = blockIdx.z*128;
  float acc = 0.f;
  #pragma unroll 4
  for (int c = c0; c < c0 + 128; c++)
    acc += W1[f*1536 + h*512 + c] * Wh1[(size_t)(h*512 + c)*512 + j];
  atomicAdd(&M1[r*512 + j], acc);
}

__global__ __launch_bounds__(256) void k_cvec_acc(
    const float* __restrict__ bc1, const float* __restrict__ Wh1, float* __restrict__ cvec1,
    const float* __restrict__ bc2, const float* __restrict__ Wh2, float* __restrict__ cvec2){
  const float* bc = blockIdx.z ? bc2 : bc1;
  const float* Wh = blockIdx.z ? Wh2 : Wh1;
  float* cvec     = blockIdx.z ? cvec2 : cvec1;
  int j = blockIdx.x*256 + threadIdx.x;
  int i0 = blockIdx.y*128;
  float acc = 0.f;
  #pragma unroll 4
  for (int i = i0; i < i0 + 128; i++) acc += bc[i] * Wh[(size_t)i*512 + j];
  atomicAdd(&cvec[j], acc);
}

// watt2 (y<6) + cvec_init (y==6): grid (2, 7)
__global__ __launch_bounds__(256) void k_watt2(const float* __restrict__ W2,
    const float* __restrict__ as_, const float* __restrict__ ad_,
    float* __restrict__ was2, float* __restrict__ wad2,
    const float* __restrict__ bh1, float* __restrict__ cvec1,
    const float* __restrict__ bh2, float* __restrict__ cvec2){
  int e = blockIdx.x*256 + threadIdx.x;
  int y = blockIdx.y;
  if (y == 6){
    cvec1[e] = bh1[e];
    cvec2[e] = bh2[e];
    return;
  }
  int kind = y / 3, h = y % 3;
  const float* att = kind ? ad_ : as_;
  const float4* row = (const float4*)(W2 + (size_t)e*1536 + h*512);
  const float4* av  = (const float4*)(att + h*512);
  float acc = 0.f;
  #pragma unroll 4
  for (int c4 = 0; c4 < 128; c4++){
    float4 wv = row[c4], a = av[c4];
    acc += wv.x*a.x + wv.y*a.y + wv.z*a.z + wv.w*a.w;
  }
  (kind ? wad2 : was2)[h*512 + e] = acc;
}

// M2 = W2_z @ Wh2_z fp32 GEMM (32x32 tiles), fused transpose+split epilogue; grid (16, 16, 3)
__global__ __launch_bounds__(256) void k_gemm_s(const float* __restrict__ A0,
    const float* __restrict__ B0, bf16* __restrict__ Th, bf16* __restrict__ Tl){
  int z = blockIdx.z;
  const float* A = A0 + (size_t)z*512;            // row stride 1536
  const float* B = B0 + (size_t)z*512*512;        // row stride 512
  __shared__ float As[16][33];
  __shared__ float Bs[16][33];
  __shared__ float tC[32][33];
  int t = threadIdx.x;
  int bm = blockIdx.y*32, bn = blockIdx.x*32;
  int tx = t & 15, ty = t >> 4;
  int ar = t >> 3, ac = (t & 7)*2;
  int br = t >> 4, bc = (t & 15)*2;
  float acc[2][2] = {};
  for (int k0 = 0; k0 < 512; k0 += 16){
    float2 av = *(const float2*)(A + (size_t)(bm+ar)*1536 + k0 + ac);
    As[ac][ar] = av.x; As[ac+1][ar] = av.y;
    float2 bv = *(const float2*)(B + (size_t)(k0+br)*512 + bn + bc);
    Bs[br][bc] = bv.x; Bs[br][bc+1] = bv.y;
    __syncthreads();
    #pragma unroll
    for (int kk = 0; kk < 16; kk++){
      float a0 = As[kk][ty*2], a1 = As[kk][ty*2+1];
      float b0 = Bs[kk][tx*2], b1 = Bs[kk][tx*2+1];
      acc[0][0] += a0*b0; acc[0][1] += a0*b1;
      acc[1][0] += a1*b0; acc[1][1] += a1*b1;
    }
    __syncthreads();
  }
  #pragma unroll
  for (int i = 0; i < 2; i++)
    #pragma unroll
    for (int j = 0; j < 2; j++)
      tC[tx*2+j][ty*2+i] = acc[i][j];             // [n_local][r_local]
  __syncthreads();
  int nl = t >> 3, c0 = (t & 7)*4;
  size_t base = (size_t)(bn + nl)*1536 + (size_t)z*512 + bm + c0;
  #pragma unroll
  for (int u = 0; u < 4; u++)
    split_store(tC[nl][c0+u], &Th[base+u], &Tl[base+u]);
}

// ======================= CSR build =======================
__global__ void k_init1(int* __restrict__ cnt1, int* __restrict__ cnt2,
                        int* __restrict__ map, float* __restrict__ bnacc){
  int i = blockIdx.x*blockDim.x + threadIdx.x;
  if (i < NN1){ cnt1[i] = 1; map[i] = -1; }
  if (i < NN2){ cnt2[i] = 1; }
  if (i < 1024){ bnacc[i] = 0.f; }
}
__global__ void k_count1(const int* __restrict__ tgt0, int* __restrict__ cnt, int E){
  int i = blockIdx.x*blockDim.x + threadIdx.x;
  if (i < E) atomicAdd(&cnt[tgt0[i]], 1);
}
__global__ void k_count2(const int* __restrict__ src0, const int* __restrict__ tgt0,
                         const int* __restrict__ map, int* __restrict__ cnt, int E){
  int i = blockIdx.x*blockDim.x + threadIdx.x;
  if (i >= E) return;
  int s = map[src0[i]], tg = map[tgt0[i]];
  if (s >= 0 && tg >= 0) atomicAdd(&cnt[tg], 1);
}
__global__ __launch_bounds__(1024) void k_scan(const int* __restrict__ counts,
    int* __restrict__ off, int* __restrict__ cur, int n){
  __shared__ int sh[1024];
  int t = threadIdx.x;
  int chunk = (n + 1023) >> 10;
  int b = t * chunk; int e = b + chunk; if (e > n) e = n;
  int s = 0;
  for (int i = b; i < e && i < n; i++) s += counts[i];
  sh[t] = s; __syncthreads();
  for (int o = 1; o < 1024; o <<= 1){
    int v = (t >= o) ? sh[t-o] : 0;
    __syncthreads();
    sh[t] += v;
    __syncthreads();
  }
  int run = (t > 0) ? sh[t-1] : 0;
  for (int i = b; i < e && i < n; i++){ int c = counts[i]; off[i] = run; cur[i] = run; run += c; }
  if (t == 1023) off[n] = sh[1023];
}
__global__ void k_fill1(const int* __restrict__ src0, const int* __restrict__ tgt0,
                        int* __restrict__ cur, int* __restrict__ esrc, int E, int nn){
  int i = blockIdx.x*blockDim.x + threadIdx.x;
  if (i >= E + nn) return;
  int s, tg;
  if (i < E){ s = src0[i]; tg = tgt0[i]; } else { s = i - E; tg = s; }
  int pos = atomicAdd(&cur[tg], 1);
  esrc[pos] = s;
}
__global__ void k_fill2(const int* __restrict__ src0, const int* __restrict__ tgt0,
                        const int* __restrict__ map, int* __restrict__ cur,
                        int* __restrict__ esrc, int E, int nn){
  int i = blockIdx.x*blockDim.x + threadIdx.x;
  if (i >= E + nn) return;
  int s, tg;
  if (i < E){
    s = map[src0[i]]; tg = map[tgt0[i]];
    if (s < 0 || tg < 0) return;
  } else { s = i - E; tg = s; }
  int pos = atomicAdd(&cur[tg], 1);
  esrc[pos] = s;
}

// ======================= layer 1: aggregate raw x (3 features) =======================
__global__ __launch_bounds__(64) void k_agg1(
    const float* __restrict__ x, const int* __restrict__ off, const int* __restrict__ esrc,
    const float* __restrict__ was, const float* __restrict__ wad,
    float* __restrict__ aggx){          // [n*9], idx h*3+f
  int n = blockIdx.x, t = threadIdx.x;  // 64 threads = 1 wave
  __shared__ float xs[MAXDEG][3];
  __shared__ float al[MAXDEG*3];
  __shared__ float mh[3], dh[3];
  int s0 = off[n]; int deg = off[n+1] - s0; if (deg > MAXDEG) deg = MAXDEG;
  float ad0, ad1, ad2;
  {
    float x0 = x[n*3], x1 = x[n*3+1], x2 = x[n*3+2];
    ad0 = x0*wad[0] + x1*wad[1] + x2*wad[2];
    ad1 = x0*wad[3] + x1*wad[4] + x2*wad[5];
    ad2 = x0*wad[6] + x1*wad[7] + x2*wad[8];
  }
  for (int e = t; e < deg; e += 64){
    int s = esrc[s0 + e];
    float x0 = x[s*3], x1 = x[s*3+1], x2 = x[s*3+2];
    xs[e][0] = x0; xs[e][1] = x1; xs[e][2] = x2;
    float v0 = x0*was[0] + x1*was[1] + x2*was[2] + ad0;
    float v1 = x0*was[3] + x1*was[4] + x2*was[5] + ad1;
    float v2 = x0*was[6] + x1*was[7] + x2*was[8] + ad2;
    al[e*3+0] = v0 > 0.f ? v0 : 0.2f*v0;
    al[e*3+1] = v1 > 0.f ? v1 : 0.2f*v1;
    al[e*3+2] = v2 > 0.f ? v2 : 0.2f*v2;
  }
  __syncthreads();
  if (t < 3){
    float m = -INFINITY;
    for (int e = 0; e < deg; e++) m = fmaxf(m, al[e*3+t]);
    float d = 0.f;
    for (int e = 0; e < deg; e++) d += expf(al[e*3+t] - m);
    mh[t] = m; dh[t] = 1.f / fmaxf(d, 1e-16f);
  }
  __syncthreads();
  float acc[9] = {0,0,0,0,0,0,0,0,0};
  for (int e = t; e < deg; e += 64){
    #pragma unroll
    for (int h = 0; h < 3; h++){
      float a = expf(al[e*3+h] - mh[h]) * dh[h];
      acc[h*3+0] += a * xs[e][0];
      acc[h*3+1] += a * xs[e][1];
      acc[h*3+2] += a * xs[e][2];
    }
  }
  #pragma unroll
  for (int q = 0; q < 9; q++){
    float v = wred64(acc[q]);
    if (t == 0) aggx[(size_t)n*9 + q] = v;
  }
}

// h1[n,j] = relu(cvec[j] + sum_q aggx[n,q]*M1[q,j]) -> bf16 ; 8 nodes per block
__global__ __launch_bounds__(256) void k_h1(const float* __restrict__ aggx,
    const float* __restrict__ M1, const float* __restrict__ cvec, bf16* __restrict__ hout){
  __shared__ float sM[9*512];
  __shared__ float sC[512];
  __shared__ float sA[8*9];
  int t = threadIdx.x; int n0 = blockIdx.x*8;
  for (int i = t; i < 9*512; i += 256) sM[i] = M1[i];
  for (int i = t; i < 512; i += 256) sC[i] = cvec[i];
  for (int i = t; i < 72; i += 256) sA[i] = aggx[(size_t)n0*9 + i];
  __syncthreads();
  #pragma unroll
  for (int i = 0; i < 8; i++){
    #pragma unroll
    for (int k2 = 0; k2 < 2; k2++){
      int j = t + k2*256;
      float a = sC[j];
      #pragma unroll
      for (int q = 0; q < 9; q++) a += sA[i*9+q] * sM[q*512+j];
      hout[(size_t)(n0+i)*512 + j] = __float2bfloat16(fmaxf(a, 0.f));
    }
  }
}

// ======================= BN / score =======================
// layer-1 partial stats over bf16 h; grid BNCH
__global__ __launch_bounds__(256) void k_bn_stats(const bf16* __restrict__ h, int M,
    float* __restrict__ psum, float* __restrict__ psq){
  int ch = blockIdx.x;
  int t = threadIdx.x;
  int c4 = (t & 127) * 4;
  int half = t >> 7;
  int rs = (M + BNCH - 1) / BNCH;
  int r0 = ch*rs, r1 = r0 + rs; if (r1 > M) r1 = M;
  float s[4] = {0,0,0,0}, q[4] = {0,0,0,0};
  for (int r = r0 + half; r < r1; r += 2){
    us4 v = *(const us4*)((const unsigned short*)h + (size_t)r*EMB + c4);
    float f0 = b2f_raw(v.x), f1 = b2f_raw(v.y), f2 = b2f_raw(v.z), f3 = b2f_raw(v.w);
    s[0]+=f0; s[1]+=f1; s[2]+=f2; s[3]+=f3;
    q[0]+=f0*f0; q[1]+=f1*f1; q[2]+=f2*f2; q[3]+=f3*f3;
  }
  __shared__ float sh[128][8];
  if (half == 1){
    #pragma unroll
    for (int u = 0; u < 4; u++){ sh[t&127][u] = s[u]; sh[t&127][4+u] = q[u]; }
  }
  __syncthreads();
  if (half == 0){
    #pragma unroll
    for (int u = 0; u < 4; u++){
      psum[(size_t)ch*EMB + c4 + u] = s[u] + sh[t][u];
      psq [(size_t)ch*EMB + c4 + u] = q[u] + sh[t][4+u];
    }
  }
}
// reduce BNCH partial chunks (COMPILE-TIME bound -> unrolled, loads pipelined) + pnorm
__global__ void k_bn_final_c(const float* __restrict__ psum, const float* __restrict__ psq,
    float* __restrict__ stats, int M, const float* __restrict__ p, float* __restrict__ pnout){
  int c = threadIdx.x;
  float s = 0.f, q = 0.f;
  #pragma unroll 16
  for (int ch = 0; ch < BNCH; ch++){
    s += psum[(size_t)ch*EMB + c];
    q += psq[(size_t)ch*EMB + c];
  }
  bn_tail(s, q, c, stats, M, p, pnout);
}
// layer-2: totals already in bnacc (no loop)
__global__ void k_bn_final_1(const float* __restrict__ bnacc,
    float* __restrict__ stats, int M, const float* __restrict__ p, float* __restrict__ pnout){
  int c = threadIdx.x;
  bn_tail(bnacc[c], bnacc[512 + c], c, stats, M, p, pnout);
}
// score only (y not materialized), bf16 h
__global__ __launch_bounds__(256) void k_score(
    const bf16* __restrict__ h, const float* __restrict__ stats,
    const float* __restrict__ g_, const float* __restrict__ be,
    const float* __restrict__ p, const float* __restrict__ pn,
    float* __restrict__ score){
  int r = blockIdx.x, t = threadIdx.x;
  float dot = 0.f;
  #pragma unroll
  for (int k = 0; k < 2; k++){
    int c = t + k*256;
    float v = (__bfloat162float(h[(size_t)r*EMB + c]) - stats[c]) * stats[512+c] * g_[c] + be[c];
    dot += v * p[c];
  }
  dot = wred64(dot);
  __shared__ float red[4];
  int lane = t & 63, wv = t >> 6;
  if (lane == 0) red[wv] = dot;
  __syncthreads();
  if (t == 0) score[r] = tanhf((red[0]+red[1]+red[2]+red[3]) / pn[0]);
}

// ======================= top-k =======================
__global__ __launch_bounds__(512) void k_topk_sort(
    const float* __restrict__ score, int* __restrict__ map,
    int* __restrict__ topi, float* __restrict__ tops, int n_per, int K){
  int g = blockIdx.x, t = threadIdx.x;     // 512 threads, 1 elem each
  __shared__ float sk[512];
  __shared__ int si[512];
  if (t < n_per){ sk[t] = score[g*n_per + t]; si[t] = t; }
  else { sk[t] = -INFINITY; si[t] = 0x7fffffff; }
  __syncthreads();
  for (int k = 2; k <= 512; k <<= 1){
    for (int j = k >> 1; j > 0; j >>= 1){
      int l = t ^ j;
      if (l > t){
        float ki = sk[t], kl = sk[l]; int ii = si[t], il = si[l];
        bool before_l = (kl > ki) || (kl == ki && il < ii);
        bool up = ((t & k) == 0);
        if (up == before_l){ sk[t]=kl; sk[l]=ki; si[t]=il; si[l]=ii; }
      }
      __syncthreads();
    }
  }
  if (t < K){
    if (map) map[g*n_per + si[t]] = g*K + t;
    topi[g*K + t] = si[t];
    tops[g*K + t] = sk[t];
  }
}

// gather + on-the-fly BN + scale -> bf16; optionally fused layer-2 attention dots
__global__ __launch_bounds__(256) void k_topk_gather(
    const bf16* __restrict__ h, const float* __restrict__ stats,
    const float* __restrict__ gm, const float* __restrict__ be,
    const int* __restrict__ topi, const float* __restrict__ tops,
    bf16* __restrict__ xn, int n_per, int K,
    const float* __restrict__ was2, const float* __restrict__ wad2,
    float* __restrict__ aso, float* __restrict__ ado){
  int row = blockIdx.x, t = threadIdx.x;
  int gr = row / K, i = row - gr*K;
  int sidx = topi[gr*K + i];
  float s = tops[gr*K + i];
  const bf16* src = h + ((size_t)(gr*n_per + sidx))*EMB;
  bf16* dst = xn + (size_t)row*EMB;
  int c0 = t, c1 = t + 256;
  float v0 = ((__bfloat162float(src[c0]) - stats[c0]) * stats[512+c0] * gm[c0] + be[c0]) * s;
  float v1 = ((__bfloat162float(src[c1]) - stats[c1]) * stats[512+c1] * gm[c1] + be[c1]) * s;
  dst[c0] = __float2bfloat16(v0);
  dst[c1] = __float2bfloat16(v1);
  if (was2){
    float a[6];
    #pragma unroll
    for (int hh = 0; hh < 3; hh++){
      a[hh]   = v0*was2[hh*512 + c0] + v1*was2[hh*512 + c1];
      a[3+hh] = v0*wad2[hh*512 + c0] + v1*wad2[hh*512 + c1];
    }
    __shared__ float red[6][4];
    int lane = t & 63, wv = t >> 6;
    #pragma unroll
    for (int q = 0; q < 6; q++){ float v = wred64(a[q]); if (lane==0) red[q][wv]=v; }
    __syncthreads();
    if (t < 6){
      float sm = red[t][0]+red[t][1]+red[t][2]+red[t][3];
      if (t < 3) aso[row*3+t] = sm; else ado[row*3+(t-3)] = sm;
    }
  }
}

// ======================= pooling (bf16 input) =======================
__global__ __launch_bounds__(256) void k_pool_partial(const bf16* __restrict__ xn,
    float* __restrict__ pmax, float* __restrict__ psum, int K){
  int g = blockIdx.x, ch = blockIdx.y, t = threadIdx.x;
  int rs = (K + 15) >> 4;
  int r0 = ch*rs, r1 = r0 + rs; if (r1 > K) r1 = K;
  #pragma unroll
  for (int k = 0; k < 2; k++){
    int c = t + k*256;
    float mx = -INFINITY, sm = 0.f;
    for (int r = r0; r < r1; r++){
      float v = __bfloat162float(xn[((size_t)(g*K + r))*EMB + c]);
      mx = fmaxf(mx, v); sm += v;
    }
    pmax[((size_t)(g*16 + ch))*EMB + c] = mx;
    psum[((size_t)(g*16 + ch))*EMB + c] = sm;
  }
}
__global__ __launch_bounds__(512) void k_pool_final(const float* __restrict__ pmax,
    const float* __restrict__ psum, float* __restrict__ cat, int K){
  int g = blockIdx.x, c = threadIdx.x;
  float mx = -INFINITY, sm = 0.f;
  #pragma unroll
  for (int ch = 0; ch < 16; ch++){
    size_t o = ((size_t)(g*16 + ch))*EMB + c;
    mx = fmaxf(mx, pmax[o]); sm += psum[o];
  }
  cat[g*1024 + c] = mx;
  cat[g*1024 + 512 + c] = sm / (float)K;
}

// ======================= layer 2 aggregation (bf16 xn input) =======================
__global__ __launch_bounds__(256) void k_agg2(
    const bf16* __restrict__ xn, const float* __restrict__ aso, const float* __restrict__ ado,
    const int* __restrict__ off, const int* __restrict__ esrc,
    bf16* __restrict__ oh){
  int n = blockIdx.x, t = threadIdx.x;
  __shared__ int srcs[MAXDEG];
  __shared__ float al[MAXDEG*3];
  __shared__ float mh[3], dh[3];
  int s0 = off[n]; int deg = off[n+1] - s0; if (deg > MAXDEG) deg = MAXDEG;
  for (int e = t; e < deg; e += 256) srcs[e] = esrc[s0 + e];
  __syncthreads();
  float ad0 = ado[n*3+0], ad1 = ado[n*3+1], ad2 = ado[n*3+2];
  for (int e = t; e < deg; e += 256){
    int s = srcs[e];
    float v0 = aso[s*3+0] + ad0, v1 = aso[s*3+1] + ad1, v2 = aso[s*3+2] + ad2;
    al[e*3+0] = v0 > 0.f ? v0 : 0.2f*v0;
    al[e*3+1] = v1 > 0.f ? v1 : 0.2f*v1;
    al[e*3+2] = v2 > 0.f ? v2 : 0.2f*v2;
  }
  __syncthreads();
  if (t < 3){
    float m = -INFINITY;
    for (int e = 0; e < deg; e++) m = fmaxf(m, al[e*3+t]);
    float d = 0.f;
    for (int e = 0; e < deg; e++) d += expf(al[e*3+t] - m);
    mh[t] = m; dh[t] = 1.f / fmaxf(d, 1e-16f);
  }
  __syncthreads();
  for (int e = t; e < deg; e += 256){
    al[e*3+0] = expf(al[e*3+0]-mh[0])*dh[0];
    al[e*3+1] = expf(al[e*3+1]-mh[1])*dh[1];
    al[e*3+2] = expf(al[e*3+2]-mh[2])*dh[2];
  }
  __syncthreads();
  float acc[2][3] = {};
  for (int e = 0; e < deg; e++){
    int s = srcs[e];
    float a0 = al[e*3], a1 = al[e*3+1], a2 = al[e*3+2];
    #pragma unroll
    for (int k = 0; k < 2; k++){
      float v = __bfloat162float(xn[(size_t)s*512 + t + k*256]);
      acc[k][0] += a0*v; acc[k][1] += a1*v; acc[k][2] += a2*v;
    }
  }
  #pragma unroll
  for (int k = 0; k < 2; k++){
    int c = t + k*256;
    #pragma unroll
    for (int h = 0; h < 3; h++)
      oh[(size_t)n*1536 + h*512 + c] = __float2bfloat16(acc[k][h]);
  }
}

// ======================= bf16-A x split-bf16-B MFMA GEMM =======================
// 128x64 tile, BK=64, XOR-swizzled LDS, double-buffered prefetch-after-barrier.
// bf16 C output + fused BN partial stats (atomicAdd into bnacc[0..511]=sum, [512..1023]=sq).
// flat grid Mtiles*8 (bm-major); wave w: rows (w>>1)*64.. x cols (w&1)*32..
__global__ __launch_bounds__(256, 2) void k_gemm_mfma(
    const bf16* __restrict__ Ah,
    const bf16* __restrict__ Bh, const bf16* __restrict__ Bl,   // [N][K] row-major
    const float* __restrict__ bias, bf16* __restrict__ C,
    float* __restrict__ bnacc,
    int M, int N, int K, int Mtiles){
  __shared__ __align__(16) unsigned short lds[2][16384];   // 64 KB total
  int t = threadIdx.x, w = t >> 6, lane = t & 63;
  int q = lane >> 4, l16 = lane & 15;
  int bmi = (int)blockIdx.x % Mtiles, bni = (int)blockIdx.x / Mtiles;
  int bm = bmi * 128, bn = bni * 64;

  int lr = lane >> 3, lc = lane & 7;
  int kg = ((lc ^ lr) & 7) * 8;          // swizzled global k element offset
  int ro = w*8 + lr;
  int m0 = bm + ro, m1 = bm + 32 + ro, m2 = bm + 64 + ro, m3 = bm + 96 + ro;
  if (m0 >= M) m0 = M-1;  if (m1 >= M) m1 = M-1;
  if (m2 >= M) m2 = M-1;  if (m3 >= M) m3 = M-1;
  int n0 = bn + ro, n1 = bn + 32 + ro;
  const bf16* ptr[8];
  ptr[0] = Ah + (size_t)m0*K + kg;
  ptr[1] = Ah + (size_t)m1*K + kg;
  ptr[2] = Ah + (size_t)m2*K + kg;
  ptr[3] = Ah + (size_t)m3*K + kg;
  ptr[4] = Bh + (size_t)n0*K + kg;
  ptr[5] = Bh + (size_t)n1*K + kg;
  ptr[6] = Bl + (size_t)n0*K + kg;
  ptr[7] = Bl + (size_t)n1*K + kg;
  const int dof[8] = {0, 2048, 4096, 6144, 8192, 10240, 12288, 14336};

  int wm = (w >> 1) * 64, wn = (w & 1) * 32;
  f32x4 acc[4][2];
  #pragma unroll
  for (int i = 0; i < 4; i++)
    #pragma unroll
    for (int j = 0; j < 2; j++)
      acc[i][j] = (f32x4){0.f, 0.f, 0.f, 0.f};

  #pragma unroll
  for (int u = 0; u < 8; u++){
    gld16(ptr[u], &lds[0][dof[u] + w*512]);
    ptr[u] += 64;
  }

  int nit = K >> 6;
  for (int it = 0; it < nit; it++){
    __syncthreads();
    int cur = it & 1;
    if (it + 1 < nit){
      int nxt = cur ^ 1;
      #pragma unroll
      for (int u = 0; u < 8; u++){
        gld16(ptr[u], &lds[nxt][dof[u] + w*512]);
        ptr[u] += 64;
      }
    }
    const unsigned short* L = lds[cur];
    #pragma unroll
    for (int ks = 0; ks < 2; ks++){
      short8 ah[4], bh2[2], bl2[2];
      int gc = ks*4 + q;
      #pragma unroll
      for (int i = 0; i < 4; i++){
        int r = wm + i*16 + l16;
        ah[i] = *(const short8*)(L + r*64 + ((gc ^ (r & 7)) << 3));
      }
      #pragma unroll
      for (int j = 0; j < 2; j++){
        int r = wn + j*16 + l16;
        int so = ((gc ^ (r & 7)) << 3);
        bh2[j] = *(const short8*)(L + 8192  + r*64 + so);
        bl2[j] = *(const short8*)(L + 12288 + r*64 + so);
      }
      #pragma unroll
      for (int i = 0; i < 4; i++)
        #pragma unroll
        for (int j = 0; j < 2; j++){
          acc[i][j] = __builtin_amdgcn_mfma_f32_16x16x32_bf16(ah[i], bh2[j], acc[i][j], 0, 0, 0);
          acc[i][j] = __builtin_amdgcn_mfma_f32_16x16x32_bf16(ah[i], bl2[j], acc[i][j], 0, 0, 0);
        }
    }
  }

  // epilogue: relu + bf16 store + per-column BN partials
  __syncthreads();                       // LDS now free for reduction scratch
  float* cs = (float*)&lds[0][0];        // [2][64] col sums | [2][64] col sqs
  float* cq = cs + 128;
  int slot = w >> 1;
  #pragma unroll
  for (int j = 0; j < 2; j++){
    int c_local = wn + j*16 + l16;
    int c = bn + c_local;
    float bv = bias ? bias[c] : 0.f;
    float ls = 0.f, lq = 0.f;
    #pragma unroll
    for (int i = 0; i < 4; i++){
      int rb = bm + wm + i*16 + q*4;
      #pragma unroll
      for (int e = 0; e < 4; e++){
        int r = rb + e;
        if (r < M){
          float v = fmaxf(acc[i][j][e] + bv, 0.f);
          C[(size_t)r*N + c] = __float2bfloat16(v);
          ls += v; lq += v*v;
        }
      }
    }
    ls += __shfl_xor(ls, 16); ls += __shfl_xor(ls, 32);
    lq += __shfl_xor(lq, 16); lq += __shfl_xor(lq, 32);
    if (q == 0){ cs[slot*64 + c_local] = ls; cq[slot*64 + c_local] = lq; }
  }
  __syncthreads();
  if (t < 64){
    atomicAdd(&bnacc[bn + t],        cs[t] + cs[64 + t]);
    atomicAdd(&bnacc[512 + bn + t],  cq[t] + cq[64 + t]);
  }
}

// ======================= head =======================
__global__ __launch_bounds__(256) void k_head1(const float* __restrict__ c1,
    const float* __restrict__ c2, const float* __restrict__ Wl1,
    const float* __restrict__ bl1, float* __restrict__ t1){
  int g = blockIdx.y;
  int jj = threadIdx.x & 63, kc = threadIdx.x >> 6;
  int j = blockIdx.x*64 + jj;
  float acc = 0.f;
  for (int k = kc*256; k < kc*256 + 256; k++){
    float xg = c1[g*1024 + k] + c2[g*1024 + k];
    acc += xg * Wl1[(size_t)k*512 + j];
  }
  __shared__ float red[4][64];
  red[kc][jj] = acc;
  __syncthreads();
  if (kc == 0){
    float v = red[0][jj]+red[1][jj]+red[2][jj]+red[3][jj] + bl1[j];
    t1[g*512 + j] = fmaxf(v, 0.f);
  }
}
__global__ __launch_bounds__(256) void k_head2(const float* __restrict__ t1,
    const float* __restrict__ Wl2, const float* __restrict__ bl2, float* __restrict__ out){
  int g = blockIdx.y;
  int jj = threadIdx.x & 63, kc = threadIdx.x >> 6;
  int j = blockIdx.x*64 + jj;
  float acc = 0.f;
  for (int k = kc*128; k < kc*128 + 128; k++)
    acc += t1[g*512 + k] * Wl2[(size_t)k*256 + j];
  __shared__ float red[4][64];
  red[kc][jj] = acc;
  __syncthreads();
  if (kc == 0)
    out[g*256 + j] = red[0][jj]+red[1][jj]+red[2][jj]+red[3][jj] + bl2[j];
}

extern "C" void kernel_launch(void* const* d_in, const int* in_sizes, int n_in,
                              void* d_out, int out_size, void* d_ws, size_t ws_size,
                              hipStream_t stream){
  const float* x   = (const float*)d_in[0];
  const int*   ei  = (const int*)d_in[1];
  const float* W1  = (const float*)d_in[2];
  const float* as1 = (const float*)d_in[3];
  const float* ad1 = (const float*)d_in[4];
  const float* bc1 = (const float*)d_in[5];
  const float* Wh1 = (const float*)d_in[6];
  const float* bh1 = (const float*)d_in[7];
  const float* g1  = (const float*)d_in[8];
  const float* be1 = (const float*)d_in[9];
  const float* p1  = (const float*)d_in[10];
  const float* W2  = (const float*)d_in[11];
  const float* as2 = (const float*)d_in[12];
  const float* ad2 = (const float*)d_in[13];
  const float* bc2 = (const float*)d_in[14];
  const float* Wh2 = (const float*)d_in[15];
  const float* bh2 = (const float*)d_in[16];
  const float* g2  = (const float*)d_in[17];
  const float* be2 = (const float*)d_in[18];
  const float* p2  = (const float*)d_in[19];
  const float* Wl1 = (const float*)d_in[20];
  const float* bl1 = (const float*)d_in[21];
  const float* Wl2 = (const float*)d_in[22];
  const float* bl2 = (const float*)d_in[23];
  float* out = (float*)d_out;

  const int* src0 = ei;
  const int* tgt0 = ei + E_EDGES;

  // ---- workspace layout ----
  bf16* Cc     = (bf16*)d_ws;                        // 8192*512 bf16 (h1 -> h2)
  bf16* xn1    = Cc + (size_t)NN1*EMB;               // 6560*512 bf16
  bf16* xn2    = xn1 + (size_t)NN2*EMB;              // 3280*512 bf16
  float* aggx1 = (float*)(xn2 + (size_t)NG*KP2*EMB + 8); // 8192*9
  float* M1    = aggx1 + (size_t)NN1*9;              // 9*512
  float* was2  = M1 + 9*EMB;                         // 3*512
  float* wad2  = was2 + 3*EMB;
  float* cvec1 = wad2 + 3*EMB;                       // 512
  float* cvec2 = cvec1 + EMB;
  float* was1  = cvec2 + EMB;                        // 16
  float* wad1  = was1 + 16;
  float* bnpsum= wad1 + 16;                          // BNCH*512
  float* bnpsq = bnpsum + (size_t)BNCH*EMB;          // BNCH*512
  float* stats = bnpsq + (size_t)BNCH*EMB;           // 1024
  float* bnacc = stats + 1024;                       // 1024 (layer-2 direct sums)
  float* pn    = bnacc + 1024;                       // 16
  float* score = pn + 16;                            // 8192
  float* cat1  = score + NN1;                        // 16*1024
  float* cat2  = cat1 + NG*1024;
  float* t1h   = cat2 + NG*1024;                     // 16*512
  float* pmax  = t1h + NG*EMB;                       // 16*16*512
  float* psum  = pmax + NG*16*EMB;
  float* aso2  = psum + NG*16*EMB;                   // 6560*3
  float* ado2  = aso2 + NN2*3;
  float* tops  = ado2 + NN2*3;                       // 16*410
  bf16* aggx2h = (bf16*)(tops + NG*KP1);             // 6560*1536 (bf16, hi only)
  bf16* M2Th   = aggx2h + (size_t)NN2*F1;            // 512*1536
  bf16* M2Tl   = M2Th + (size_t)EMB*F1;
  int* map     = (int*)(M2Tl + (size_t)EMB*F1);      // 8192
  int* cnt1    = map + NN1;
  int* off1    = cnt1 + NN1;                         // 8200
  int* cur1    = off1 + NN1 + 8;
  int* esrc1   = cur1 + NN1;                         // 139264
  int* cnt2    = esrc1 + (E_EDGES + NN1);
  int* off2    = cnt2 + NN2;                         // 6568
  int* cur2    = off2 + NN2 + 8;
  int* esrc2   = cur2 + NN2;                         // 137700 (pad)
  int* topi    = esrc2 + 137700;                     // 16*410

  // ---- precompute ----
  k_init1<<<(NN1+255)/256,256,0,stream>>>(cnt1,cnt2,map,bnacc);
  k_watt1<<<18,64,0,stream>>>(W1,as1,ad1,was1,wad1,M1);
  k_m1_acc<<<dim3(2,9,4),256,0,stream>>>(W1,Wh1,M1);
  k_watt2<<<dim3(2,7),256,0,stream>>>(W2,as2,ad2,was2,wad2,bh1,cvec1,bh2,cvec2);
  k_cvec_acc<<<dim3(2,12,2),256,0,stream>>>(bc1,Wh1,cvec1,bc2,Wh2,cvec2);
  k_gemm_s<<<dim3(16,16,3),256,0,stream>>>(W2,Wh2,M2Th,M2Tl);

  // ---- layer 1 ----
  k_count1<<<(E_EDGES+255)/256,256,0,stream>>>(tgt0,cnt1,E_EDGES);
  k_scan<<<1,1024,0,stream>>>(cnt1,off1,cur1,NN1);
  k_fill1<<<(E_EDGES+NN1+255)/256,256,0,stream>>>(src0,tgt0,cur1,esrc1,E_EDGES,NN1);
  k_agg1<<<NN1,64,0,stream>>>(x,off1,esrc1,was1,wad1,aggx1);
  k_h1<<<NN1/8,256,0,stream>>>(aggx1,M1,cvec1,Cc);
  k_bn_stats<<<BNCH,256,0,stream>>>(Cc,NN1,bnpsum,bnpsq);
  k_bn_final_c<<<1,512,0,stream>>>(bnpsum,bnpsq,stats,NN1,p1,pn);
  k_score<<<NN1,256,0,stream>>>(Cc,stats,g1,be1,p1,pn,score);
  k_topk_sort<<<NG,512,0,stream>>>(score,map,topi,tops,NP1,KP1);
  k_topk_gather<<<NG*KP1,256,0,stream>>>(Cc,stats,g1,be1,topi,tops,xn1,NP1,KP1,
      was2,wad2,aso2,ado2);
  k_pool_partial<<<dim3(NG,16),256,0,stream>>>(xn1,pmax,psum,KP1);
  k_pool_final<<<NG,512,0,stream>>>(pmax,psum,cat1,KP1);

  // ---- layer 2 ----
  k_count2<<<(E_EDGES+255)/256,256,0,stream>>>(src0,tgt0,map,cnt2,E_EDGES);
  k_scan<<<1,1024,0,stream>>>(cnt2,off2,cur2,NN2);
  k_fill2<<<(E_EDGES+NN2+255)/256,256,0,stream>>>(src0,tgt0,map,cur2,esrc2,E_EDGES,NN2);
  k_agg2<<<NN2,256,0,stream>>>(xn1,aso2,ado2,off2,esrc2,aggx2h);
  k_gemm_mfma<<<52*8,256,0,stream>>>(aggx2h,M2Th,M2Tl,cvec2,Cc,bnacc,NN2,EMB,F1,52);
  k_bn_final_1<<<1,512,0,stream>>>(bnacc,stats,NN2,p2,pn+1);
  k_score<<<NN2,256,0,stream>>>(Cc,stats,g2,be2,p2,pn+1,score);
  k_topk_sort<<<NG,512,0,stream>>>(score,(int*)nullptr,topi,tops,KP1,KP2);
  k_topk_gather<<<NG*KP2,256,0,stream>>>(Cc,stats,g2,be2,topi,tops,xn2,KP1,KP2,
      (const float*)nullptr,(const float*)nullptr,(float*)nullptr,(float*)nullptr);
  k_pool_partial<<<dim3(NG,16),256,0,stream>>>(xn2,pmax,psum,KP2);
  k_pool_final<<<NG,512,0,stream>>>(pmax,psum,cat2,KP2);

  // ---- head ----
  k_head1<<<dim3(8,NG),256,0,stream>>>(cat1,cat2,Wl1,bl1,t1h);
  k_head2<<<dim3(4,NG),256,0,stream>>>(t1h,Wl2,bl2,out);
}